// Round 7
// baseline (79.193 us; speedup 1.0000x reference)
//
#include <hip/hip_runtime.h>
#include <hip/hip_cooperative_groups.h>

namespace cg = cooperative_groups;

// SuperPointMatchesGenerator: B=8, N0=N1=2048 mutual-NN under homography.
// d_out f32, concat: gt_matches0[8,2048] | gt_matches1[8,2048] | min_dist0[8,2048]
//
// R16 = cooperative single-dispatch fusion of R15's {prep, main, final}.
// R15 post-mortem: 78.9us PASS; fill ~41us (harness-fixed, 83% HBM peak);
// our 3 dispatches ~20-25us of exec leave ~12-20us of launch/gap overhead as
// the dominant controllable cost. Lever = dispatch count (guide: cooperative
// launch is supported by the grading harness).
//  - ONE kernel, grid 1024x256, LDS padded to 40KB -> exactly 4 blocks/CU
//    (LDS-bound 160/40) -> 1024 co-resident deterministically: satisfies
//    cooperative capacity AND fixes R15's pass imbalance (2048 blocks at
//    5/CU = 1280+768 tail; now each block runs its m0 tile then m1 tile).
//  - phase0 = prep body (t<32768); grid.sync(); phase1 = R15 main body x2
//    halves (bit-identical math; __syncthreads guards LDS reuse between
//    halves); grid.sync(); phase2 = final body (t<16384).
//  - rails: one-time host check {cooperativeLaunch attr, occupancy*CU >=
//    1024}; any failure OR launch error -> R15-proven 3-dispatch fallback.
//
// FP exactness vs numpy-f32 (no FMA contraction, explicit __f*_rn):
//   p_i = (H[i0]*x + H[i1]*y) + H[i2];  X = p0/(p2+1e-8);  a2 = X*X + Y*Y;
//   d2  = (a2 + b2) - (rx2*x + ry2*y)  [rx2=2rx pre-doubled: bit-exact];
//   winner e = sqrt(max(d2,0)); clamp at key-pack (passed R9/R10/R13/R15).
// Keep-first argmin: u64 (d2bits<<32|idx) min; per-thread candidates ascend;
// strict < at every level => smallest index among equal d2.
//
// ws: q0 f4[16K] | q1 f4[16K] | gt0p u16[16K] | gt1 u16[16K]  (576KB)

#define SPN 2048
#define SPT 16384
#define CGRID 1024   // cooperative grid: 1024 blocks x 256 threads
#define HGRID (SPT / 16)

__device__ __forceinline__ void sp_reproject(const float* __restrict__ T, int b,
                                             float x, float y,
                                             float& X, float& Y, float& S) {
  const float* H = T + b * 9;
  float p0 = __fadd_rn(__fadd_rn(__fmul_rn(H[0], x), __fmul_rn(H[1], y)), H[2]);
  float p1 = __fadd_rn(__fadd_rn(__fmul_rn(H[3], x), __fmul_rn(H[4], y)), H[5]);
  float p2 = __fadd_rn(__fadd_rn(__fmul_rn(H[6], x), __fmul_rn(H[7], y)), H[8]);
  float den = __fadd_rn(p2, 1e-8f);
  X = __fdiv_rn(p0, den);
  Y = __fdiv_rn(p1, den);
  S = __fadd_rn(__fmul_rn(X, X), __fmul_rn(Y, Y));
}

// ==================== cooperative mega-kernel ====================
__global__ __launch_bounds__(256, 4) void SuperPointMatchesGenerator_56925496541369_kernel(
    const float2* __restrict__ k0, const float2* __restrict__ k1,
    const float* __restrict__ T, float4* __restrict__ q0, float4* __restrict__ q1,
    unsigned short* __restrict__ gt0p, unsigned short* __restrict__ gt1,
    float* __restrict__ out) {
  cg::grid_group grid = cg::this_grid();
  __shared__ float4 cand[SPN + 512];              // 40960B: forces 4 blocks/CU
  const int tid = threadIdx.x;
  const int gt = (int)blockIdx.x * 256 + tid;
  float* __restrict__ out_mind = out + 2 * SPT;

  // ---- phase 0: prep (identical values to R15's sp_prep) ----
  if (gt < 2 * SPT) {
    if (gt < SPT) {
      float2 p = k0[gt];
      float X, Y, S;
      sp_reproject(T, gt >> 11, p.x, p.y, X, Y, S);
      q0[gt] = make_float4(X, Y, S, 0.0f);
    } else {
      int u = gt - SPT;
      float2 p = k1[u];
      float S = __fadd_rn(__fmul_rn(p.x, p.x), __fmul_rn(p.y, p.y));
      q1[u] = make_float4(p.x, p.y, S, 0.0f);
    }
  }
  grid.sync();

  // ---- phase 1: main, two halves per block (m0 tile then m1 tile) ----
  for (int half = 0; half < 2; half++) {
    __syncthreads();                              // protect cand/keys reuse
    const bool m1 = (half == 1);
    const int base = (int)blockIdx.x << 4;        // 16 rows
    const int b = base >> 11, cb = b << 11;
    const float4* __restrict__ qr = m1 ? q1 : q0;
    const float4* __restrict__ qc = (m1 ? q0 : q1) + cb;

    float4 stage[8];
#pragma unroll
    for (int k = 0; k < 8; k++) stage[k] = qc[(k << 8) + tid];
#pragma unroll
    for (int k = 0; k < 8; k++) cand[(k << 8) + tid] = stage[k];

    float rx2[16], ry2[16], rsv[16], bv[16];
    int bi[16];
#pragma unroll
    for (int r = 0; r < 16; r++) {
      float4 v = qr[base + r];                    // uniform -> SGPR broadcast
      rx2[r] = __fmul_rn(2.0f, v.x);              // exact x2
      ry2[r] = __fmul_rn(2.0f, v.y);
      rsv[r] = v.z;
      bv[r] = INFINITY; bi[r] = 0;
    }
    __syncthreads();

    float4 vv[8];
#pragma unroll
    for (int k = 0; k < 8; k++) vv[k] = cand[(k << 8) + tid];
#pragma unroll
    for (int k = 0; k < 8; k++) {
      const int c = (k << 8) + tid;               // ascending per thread
#pragma unroll
      for (int r = 0; r < 16; r++) {
        float tw = __fadd_rn(__fmul_rn(rx2[r], vv[k].x), __fmul_rn(ry2[r], vv[k].y));
        float s  = __fadd_rn(rsv[r], vv[k].z);
        float d2 = __fsub_rn(s, tw);
        if (d2 < bv[r]) { bv[r] = d2; bi[r] = c; }
      }
    }
    __syncthreads();                              // all cand reads done

    unsigned long long* keys = (unsigned long long*)cand;
#pragma unroll
    for (int r = 0; r < 16; r++) {
      float dm = fmaxf(bv[r], 0.0f);              // clamp once (see header)
      keys[(r << 8) + tid] =
          ((unsigned long long)__float_as_uint(dm) << 32) | (unsigned)bi[r];
    }
    __syncthreads();

    const int wv = tid >> 6, ln = tid & 63;
#pragma unroll
    for (int rr = 0; rr < 4; rr++) {
      const int r = (wv << 2) + rr;
      unsigned long long kk = keys[(r << 8) + ln];
      unsigned long long t;
      t = keys[(r << 8) + 64 + ln];  if (t < kk) kk = t;
      t = keys[(r << 8) + 128 + ln]; if (t < kk) kk = t;
      t = keys[(r << 8) + 192 + ln]; if (t < kk) kk = t;
#pragma unroll
      for (int off = 32; off > 0; off >>= 1) {
        unsigned long long o = __shfl_down(kk, off);
        if (o < kk) kk = o;
      }
      if (ln == 0) {
        int idx = (int)(kk & 0x7ffu);
        if (!m1) {
          float e = __fsqrt_rn(__uint_as_float((unsigned)(kk >> 32)));
          unsigned short pk = (unsigned short)idx;
          if (e > 3.0f) pk |= 0x8000u;            // strict >, exact fp32
          gt0p[base + r] = pk;
          out_mind[base + r] = e;
        } else {
          gt1[base + r] = (unsigned short)idx;
        }
      }
    }
  }
  grid.sync();

  // ---- phase 2: final (identical to R15's final) ----
  if (gt < SPT) {
    int b2 = gt >> 11, i = gt & 2047, cb2 = b2 << 11;
    unsigned short p0 = gt0p[gt];
    int m0i = p0 & 0x7ff;
    bool ok0 = ((p0 & 0x8000u) == 0) && ((int)gt1[cb2 + m0i] == i);
    out[gt] = ok0 ? (float)m0i : -1.0f;

    int istar = gt1[gt];
    unsigned short ps = gt0p[cb2 + istar];
    bool ok1 = (((int)(ps & 0x7ff)) == i) && ((ps & 0x8000u) == 0);
    out[SPT + gt] = ok1 ? (float)istar : -1.0f;
  }
}

// ==================== R15-proven 3-dispatch fallback ====================
__global__ __launch_bounds__(256) void sp_prep(
    const float2* __restrict__ k0, const float2* __restrict__ k1,
    const float* __restrict__ T, float4* __restrict__ q0, float4* __restrict__ q1) {
  int t = blockIdx.x * 256 + threadIdx.x;
  if (t < SPT) {
    float2 p = k0[t];
    float X, Y, S;
    sp_reproject(T, t >> 11, p.x, p.y, X, Y, S);
    q0[t] = make_float4(X, Y, S, 0.0f);
  } else {
    int u = t - SPT;
    float2 p = k1[u];
    float S = __fadd_rn(__fmul_rn(p.x, p.x), __fmul_rn(p.y, p.y));
    q1[u] = make_float4(p.x, p.y, S, 0.0f);
  }
}

__global__ __launch_bounds__(256, 4) void sp_main3(
    const float4* __restrict__ q0, const float4* __restrict__ q1,
    unsigned short* __restrict__ gt0p, unsigned short* __restrict__ gt1,
    float* __restrict__ out_mind) {
  __shared__ float4 cand[SPN];
  const int tid = threadIdx.x;
  const bool m1 = blockIdx.x >= HGRID;
  const int base = (m1 ? blockIdx.x - HGRID : blockIdx.x) << 4;
  const int b = base >> 11, cb = b << 11;
  const float4* __restrict__ qr = m1 ? q1 : q0;
  const float4* __restrict__ qc = (m1 ? q0 : q1) + cb;

  float4 stage[8];
#pragma unroll
  for (int k = 0; k < 8; k++) stage[k] = qc[(k << 8) + tid];
#pragma unroll
  for (int k = 0; k < 8; k++) cand[(k << 8) + tid] = stage[k];

  float rx2[16], ry2[16], rsv[16], bv[16];
  int bi[16];
#pragma unroll
  for (int r = 0; r < 16; r++) {
    float4 v = qr[base + r];
    rx2[r] = __fmul_rn(2.0f, v.x);
    ry2[r] = __fmul_rn(2.0f, v.y);
    rsv[r] = v.z;
    bv[r] = INFINITY; bi[r] = 0;
  }
  __syncthreads();

  float4 vv[8];
#pragma unroll
  for (int k = 0; k < 8; k++) vv[k] = cand[(k << 8) + tid];
#pragma unroll
  for (int k = 0; k < 8; k++) {
    const int c = (k << 8) + tid;
#pragma unroll
    for (int r = 0; r < 16; r++) {
      float tw = __fadd_rn(__fmul_rn(rx2[r], vv[k].x), __fmul_rn(ry2[r], vv[k].y));
      float s  = __fadd_rn(rsv[r], vv[k].z);
      float d2 = __fsub_rn(s, tw);
      if (d2 < bv[r]) { bv[r] = d2; bi[r] = c; }
    }
  }
  __syncthreads();

  unsigned long long* keys = (unsigned long long*)cand;
#pragma unroll
  for (int r = 0; r < 16; r++) {
    float dm = fmaxf(bv[r], 0.0f);
    keys[(r << 8) + tid] =
        ((unsigned long long)__float_as_uint(dm) << 32) | (unsigned)bi[r];
  }
  __syncthreads();

  const int wv = tid >> 6, ln = tid & 63;
#pragma unroll
  for (int rr = 0; rr < 4; rr++) {
    const int r = (wv << 2) + rr;
    unsigned long long kk = keys[(r << 8) + ln];
    unsigned long long t;
    t = keys[(r << 8) + 64 + ln];  if (t < kk) kk = t;
    t = keys[(r << 8) + 128 + ln]; if (t < kk) kk = t;
    t = keys[(r << 8) + 192 + ln]; if (t < kk) kk = t;
#pragma unroll
    for (int off = 32; off > 0; off >>= 1) {
      unsigned long long o = __shfl_down(kk, off);
      if (o < kk) kk = o;
    }
    if (ln == 0) {
      int idx = (int)(kk & 0x7ffu);
      if (!m1) {
        float e = __fsqrt_rn(__uint_as_float((unsigned)(kk >> 32)));
        unsigned short pk = (unsigned short)idx;
        if (e > 3.0f) pk |= 0x8000u;
        gt0p[base + r] = pk;
        out_mind[base + r] = e;
      } else {
        gt1[base + r] = (unsigned short)idx;
      }
    }
  }
}

__global__ __launch_bounds__(256) void sp_final3(
    const unsigned short* __restrict__ gt0p, const unsigned short* __restrict__ gt1,
    float* __restrict__ out) {
  int t = blockIdx.x * 256 + threadIdx.x;
  if (t >= SPT) return;
  int b = t >> 11, i = t & 2047, cb = b << 11;

  unsigned short p0 = gt0p[t];
  int m0 = p0 & 0x7ff;
  bool ok0 = ((p0 & 0x8000u) == 0) && ((int)gt1[cb + m0] == i);
  out[t] = ok0 ? (float)m0 : -1.0f;

  int istar = gt1[t];
  unsigned short ps = gt0p[cb + istar];
  bool ok1 = (((int)(ps & 0x7ff)) == i) && ((ps & 0x8000u) == 0);
  out[SPT + t] = ok1 ? (float)istar : -1.0f;
}

extern "C" void kernel_launch(void* const* d_in, const int* in_sizes, int n_in,
                              void* d_out, int out_size, void* d_ws, size_t ws_size,
                              hipStream_t stream) {
  (void)in_sizes; (void)n_in; (void)out_size; (void)ws_size;
  const float2* k0 = (const float2*)d_in[0];
  const float2* k1 = (const float2*)d_in[1];
  const float* T   = (const float*)d_in[2];
  float* out = (float*)d_out;

  float4* q0 = (float4*)d_ws;                          // 256 KB
  float4* q1 = q0 + SPT;                               // 256 KB
  unsigned short* gt0p = (unsigned short*)(q1 + SPT);  // 32 KB
  unsigned short* gt1  = gt0p + SPT;                   // 32 KB

  // one-time capability check (host-only queries; no stream ops -> capture-safe)
  static int coop_state = -1;
  if (coop_state < 0) {
    int dev = 0, attr = 0, ncu = 0, maxb = 0;
    (void)hipGetDevice(&dev);
    (void)hipDeviceGetAttribute(&attr, hipDeviceAttributeCooperativeLaunch, dev);
    (void)hipDeviceGetAttribute(&ncu, hipDeviceAttributeMultiprocessorCount, dev);
    hipError_t oe = hipOccupancyMaxActiveBlocksPerMultiprocessor(
        &maxb, SuperPointMatchesGenerator_56925496541369_kernel, 256, 0);
    coop_state = (attr != 0 && oe == hipSuccess && (long)maxb * ncu >= CGRID) ? 1 : 0;
  }

  if (coop_state == 1) {
    void* args[] = {(void*)&k0, (void*)&k1, (void*)&T, (void*)&q0, (void*)&q1,
                    (void*)&gt0p, (void*)&gt1, (void*)&out};
    hipError_t le = hipLaunchCooperativeKernel(
        SuperPointMatchesGenerator_56925496541369_kernel,
        dim3(CGRID), dim3(256), args, 0, stream);
    if (le == hipSuccess) return;
    coop_state = 0;  // fall through to proven path
  }

  sp_prep<<<2 * SPT / 256, 256, 0, stream>>>(k0, k1, T, q0, q1);
  sp_main3<<<2 * HGRID, 256, 0, stream>>>(q0, q1, gt0p, gt1, out + 2 * SPT);
  sp_final3<<<SPT / 256, 256, 0, stream>>>(gt0p, gt1, out);
}